// Round 1
// baseline (644.477 us; speedup 1.0000x reference)
//
#include <hip/hip_runtime.h>
#include <hip/hip_bf16.h>
#include <stdint.h>

#define AS1 __attribute__((address_space(1)))
#define AS3 __attribute__((address_space(3)))

typedef float f32x4 __attribute__((ext_vector_type(4)));
typedef __bf16 bf16x8 __attribute__((ext_vector_type(8)));

static __device__ __forceinline__ unsigned short f2bf(float f) {
  unsigned u = __float_as_uint(f);
  u += 0x7fff + ((u >> 16) & 1);   // RNE
  return (unsigned short)(u >> 16);
}

// ---------------- conversion kernels ----------------

__global__ __launch_bounds__(256) void k_f32_to_bf16(const float* __restrict__ in,
                                                     unsigned short* __restrict__ out, int n4) {
  int i = blockIdx.x * 256 + threadIdx.x;
  if (i >= n4) return;
  float4 v = reinterpret_cast<const float4*>(in)[i];
  ushort4 o;
  o.x = f2bf(v.x); o.y = f2bf(v.y); o.z = f2bf(v.z); o.w = f2bf(v.w);
  reinterpret_cast<ushort4*>(out)[i] = o;
}

// transpose + convert the four 512x512 weights: out[n*512+k] = bf16(w[k*512+n])
__global__ __launch_bounds__(256) void k_wtrans(const float* __restrict__ w0, const float* __restrict__ w1,
                                                const float* __restrict__ w2, const float* __restrict__ w3,
                                                unsigned short* __restrict__ o0, unsigned short* __restrict__ o1,
                                                unsigned short* __restrict__ o2, unsigned short* __restrict__ o3) {
  const float* w; unsigned short* o;
  switch (blockIdx.y) {
    case 0: w = w0; o = o0; break;
    case 1: w = w1; o = o1; break;
    case 2: w = w2; o = o2; break;
    default: w = w3; o = o3; break;
  }
  int idx = blockIdx.x * 256 + threadIdx.x;   // 0..262143
  int kk = idx >> 9;
  int n  = idx & 511;
  o[n * 512 + kk] = f2bf(w[idx]);
}

// ---------------- GEMM: C[M,N] = A[M,K] * Bt[N,K]^T (+bias) ----------------
// m97 structure: 128x128 tile, BK=32, 4 waves (each 64x64 = 4x4 frags of 16x16),
// global_load_lds width 16, mfma_f32_16x16x32_bf16.
// TRANS_OUT: write bf16 transposed per 4096-row batch: out[(gr>>12)][gc][gr&4095]

template<int OUT_F32, int HAS_BIAS, int TRANS_OUT>
__global__ __launch_bounds__(256) void k_gemm_bt(
    const unsigned short* __restrict__ A, const unsigned short* __restrict__ Bt,
    const float* __restrict__ bias, void* __restrict__ Cout,
    int M, int N, int K, int ldc)
{
  __shared__ unsigned short sA[128 * 32];
  __shared__ unsigned short sB[128 * 32];
  const int tid = threadIdx.x;
  const int tileM = blockIdx.y * 128;
  const int tileN = blockIdx.x * 128;
  const unsigned short* Ab = A + (size_t)tileM * K;
  const unsigned short* Bb = Bt + (size_t)tileN * K;

  f32x4 acc[4][4];
#pragma unroll
  for (int m = 0; m < 4; ++m)
#pragma unroll
    for (int n = 0; n < 4; ++n)
      acc[m][n] = (f32x4){0.f, 0.f, 0.f, 0.f};

  const int lane = tid & 63;
  const int w = tid >> 6;
  const int wr = (w >> 1) * 64;
  const int wc = (w & 1) * 64;
  const int fr = lane & 15;          // fragment row (m or n within 16)
  const int fk = (lane >> 4) * 8;    // k offset within 32

  for (int k0 = 0; k0 < K; k0 += 32) {
    __syncthreads();
#pragma unroll
    for (int i = 0; i < 2; ++i) {
      int c = tid + i * 256;         // chunk id 0..511 (16B chunks)
      int r = c >> 2;                // row 0..127
      int cb = (c & 3) * 8;          // element offset in row (8 bf16 = 16B)
      __builtin_amdgcn_global_load_lds((const AS1 void*)(Ab + (size_t)r * K + k0 + cb),
                                       (AS3 void*)(&sA[c * 8]), 16, 0, 0);
      __builtin_amdgcn_global_load_lds((const AS1 void*)(Bb + (size_t)r * K + k0 + cb),
                                       (AS3 void*)(&sB[c * 8]), 16, 0, 0);
    }
    __syncthreads();

    bf16x8 af[4], bfr[4];
#pragma unroll
    for (int m = 0; m < 4; ++m)
      af[m] = *reinterpret_cast<const bf16x8*>(&sA[(wr + m * 16 + fr) * 32 + fk]);
#pragma unroll
    for (int n = 0; n < 4; ++n)
      bfr[n] = *reinterpret_cast<const bf16x8*>(&sB[(wc + n * 16 + fr) * 32 + fk]);
#pragma unroll
    for (int m = 0; m < 4; ++m)
#pragma unroll
      for (int n = 0; n < 4; ++n)
        acc[m][n] = __builtin_amdgcn_mfma_f32_16x16x32_bf16(af[m], bfr[n], acc[m][n], 0, 0, 0);
  }

  // epilogue: C frag layout col=lane&15, row=(lane>>4)*4+reg  [m89 verified]
  const int col4 = lane & 15;
  const int rw4 = (lane >> 4) * 4;
#pragma unroll
  for (int n = 0; n < 4; ++n) {
    const int gc = tileN + wc + n * 16 + col4;
    const float bval = HAS_BIAS ? bias[gc] : 0.0f;
#pragma unroll
    for (int m = 0; m < 4; ++m) {
      const int gr = tileM + wr + m * 16 + rw4;
#pragma unroll
      for (int j = 0; j < 4; ++j) {
        float v = acc[m][n][j] + bval;
        if (TRANS_OUT) {
          size_t idx = ((size_t)((gr + j) >> 12)) * (512u * 4096u) + (size_t)gc * 4096u
                       + (size_t)((gr + j) & 4095);
          ((unsigned short*)Cout)[idx] = f2bf(v);
        } else if (OUT_F32) {
          ((float*)Cout)[(size_t)(gr + j) * ldc + gc] = v;
        } else {
          ((unsigned short*)Cout)[(size_t)(gr + j) * ldc + gc] = f2bf(v);
        }
      }
    }
  }
}

// ---------------- row softmax (4096 cols), one block per row ----------------

__global__ __launch_bounds__(256) void k_softmax_f32(const float* __restrict__ S,
                                                     unsigned short* __restrict__ P) {
  const int row = blockIdx.x;
  const float4* src = reinterpret_cast<const float4*>(S + (size_t)row * 4096);
  ushort4* dst = reinterpret_cast<ushort4*>(P + (size_t)row * 4096);
  const int tid = threadIdx.x;
  float4 v[4];
  float m = -3.0e38f;
#pragma unroll
  for (int i = 0; i < 4; ++i) {
    v[i] = src[tid + i * 256];
    m = fmaxf(m, fmaxf(fmaxf(v[i].x, v[i].y), fmaxf(v[i].z, v[i].w)));
  }
#pragma unroll
  for (int off = 32; off >= 1; off >>= 1) m = fmaxf(m, __shfl_xor(m, off));
  __shared__ float redm[4], reds[4];
  const int wv = tid >> 6, ln = tid & 63;
  if (ln == 0) redm[wv] = m;
  __syncthreads();
  m = fmaxf(fmaxf(redm[0], redm[1]), fmaxf(redm[2], redm[3]));
  float s = 0.f;
#pragma unroll
  for (int i = 0; i < 4; ++i) {
    v[i].x = __expf(v[i].x - m); v[i].y = __expf(v[i].y - m);
    v[i].z = __expf(v[i].z - m); v[i].w = __expf(v[i].w - m);
    s += v[i].x + v[i].y + v[i].z + v[i].w;
  }
#pragma unroll
  for (int off = 32; off >= 1; off >>= 1) s += __shfl_xor(s, off);
  if (ln == 0) reds[wv] = s;
  __syncthreads();
  s = reds[0] + reds[1] + reds[2] + reds[3];
  const float inv = 1.0f / s;
#pragma unroll
  for (int i = 0; i < 4; ++i) {
    ushort4 o;
    o.x = f2bf(v[i].x * inv); o.y = f2bf(v[i].y * inv);
    o.z = f2bf(v[i].z * inv); o.w = f2bf(v[i].w * inv);
    dst[tid + i * 256] = o;
  }
}

// fallback: scores stored bf16, softmax in place (each block touches only its own row)
__global__ __launch_bounds__(256) void k_softmax_bf16(unsigned short* __restrict__ S) {
  const int row = blockIdx.x;
  ushort4* ptr = reinterpret_cast<ushort4*>(S + (size_t)row * 4096);
  const int tid = threadIdx.x;
  float v[16];
  float m = -3.0e38f;
#pragma unroll
  for (int i = 0; i < 4; ++i) {
    ushort4 u = ptr[tid + i * 256];
    v[i * 4 + 0] = __uint_as_float(((unsigned)u.x) << 16);
    v[i * 4 + 1] = __uint_as_float(((unsigned)u.y) << 16);
    v[i * 4 + 2] = __uint_as_float(((unsigned)u.z) << 16);
    v[i * 4 + 3] = __uint_as_float(((unsigned)u.w) << 16);
#pragma unroll
    for (int j = 0; j < 4; ++j) m = fmaxf(m, v[i * 4 + j]);
  }
#pragma unroll
  for (int off = 32; off >= 1; off >>= 1) m = fmaxf(m, __shfl_xor(m, off));
  __shared__ float redm[4], reds[4];
  const int wv = tid >> 6, ln = tid & 63;
  if (ln == 0) redm[wv] = m;
  __syncthreads();
  m = fmaxf(fmaxf(redm[0], redm[1]), fmaxf(redm[2], redm[3]));
  float s = 0.f;
#pragma unroll
  for (int i = 0; i < 16; ++i) { v[i] = __expf(v[i] - m); s += v[i]; }
#pragma unroll
  for (int off = 32; off >= 1; off >>= 1) s += __shfl_xor(s, off);
  if (ln == 0) reds[wv] = s;
  __syncthreads();
  s = reds[0] + reds[1] + reds[2] + reds[3];
  const float inv = 1.0f / s;
#pragma unroll
  for (int i = 0; i < 4; ++i) {
    ushort4 o;
    o.x = f2bf(v[i * 4 + 0] * inv); o.y = f2bf(v[i * 4 + 1] * inv);
    o.z = f2bf(v[i * 4 + 2] * inv); o.w = f2bf(v[i * 4 + 3] * inv);
    ptr[tid + i * 256] = o;
  }
}

// ---------------- launch ----------------

extern "C" void kernel_launch(void* const* d_in, const int* in_sizes, int n_in,
                              void* d_out, int out_size, void* d_ws, size_t ws_size,
                              hipStream_t stream) {
  const float* query  = (const float*)d_in[0];
  const float* target = (const float*)d_in[1];
  const float* wq = (const float*)d_in[2];
  const float* bq = (const float*)d_in[3];
  const float* wk = (const float*)d_in[4];
  const float* bk = (const float*)d_in[5];
  const float* wv = (const float*)d_in[6];
  const float* bv = (const float*)d_in[7];
  const float* wo = (const float*)d_in[8];
  const float* bo = (const float*)d_in[9];
  float* out = (float*)d_out;

  const size_t NTOK = (size_t)4 * 4096;          // 16384 rows total
  const size_t SZ_BF = NTOK * 512 * sizeof(unsigned short);  // 16 MB

  char* ws = (char*)d_ws;
  size_t off = 0;
  unsigned short* query_bf  = (unsigned short*)(ws + off); off += SZ_BF;
  unsigned short* target_bf = (unsigned short*)(ws + off); off += SZ_BF;
  unsigned short* q_bf      = (unsigned short*)(ws + off); off += SZ_BF;
  unsigned short* k_bf      = (unsigned short*)(ws + off); off += SZ_BF;
  unsigned short* v_t       = (unsigned short*)(ws + off); off += SZ_BF;  // [B][512][4096]
  unsigned short* ctx       = (unsigned short*)(ws + off); off += SZ_BF;
  unsigned short* wq_t = (unsigned short*)(ws + off); off += 512 * 512 * 2;
  unsigned short* wk_t = (unsigned short*)(ws + off); off += 512 * 512 * 2;
  unsigned short* wv_t = (unsigned short*)(ws + off); off += 512 * 512 * 2;
  unsigned short* wo_t = (unsigned short*)(ws + off); off += 512 * 512 * 2;
  unsigned short* Pbuf = (unsigned short*)(ws + off); off += (size_t)4096 * 4096 * 2;  // 32 MB
  float* Sf = (float*)(ws + off);
  const bool useF32S = (ws_size >= off + (size_t)4096 * 4096 * 4);

  // 1) convert inputs to bf16
  k_f32_to_bf16<<<8192, 256, 0, stream>>>(query,  query_bf,  2097152);
  k_f32_to_bf16<<<8192, 256, 0, stream>>>(target, target_bf, 2097152);
  // 2) weights -> bf16 transposed ([N][K])
  k_wtrans<<<dim3(1024, 4), 256, 0, stream>>>(wq, wk, wv, wo, wq_t, wk_t, wv_t, wo_t);

  // 3) projections  (M=16384, N=512, K=512)
  dim3 gProj(512 / 128, 16384 / 128);
  k_gemm_bt<0, 1, 0><<<gProj, 256, 0, stream>>>(query_bf,  wq_t, bq, q_bf, 16384, 512, 512, 512);
  k_gemm_bt<0, 1, 0><<<gProj, 256, 0, stream>>>(target_bf, wk_t, bk, k_bf, 16384, 512, 512, 512);
  k_gemm_bt<0, 1, 1><<<gProj, 256, 0, stream>>>(target_bf, wv_t, bv, v_t,  16384, 512, 512, 512);

  // 4) per-batch attention
  for (int b = 0; b < 4; ++b) {
    const unsigned short* qb  = q_bf + (size_t)b * 4096 * 512;
    const unsigned short* kb  = k_bf + (size_t)b * 4096 * 512;
    const unsigned short* vtb = v_t  + (size_t)b * 512 * 4096;
    unsigned short* ctxb = ctx + (size_t)b * 4096 * 512;
    if (useF32S) {
      k_gemm_bt<1, 0, 0><<<dim3(32, 32), 256, 0, stream>>>(qb, kb, nullptr, Sf, 4096, 4096, 512, 4096);
      k_softmax_f32<<<4096, 256, 0, stream>>>(Sf, Pbuf);
    } else {
      k_gemm_bt<0, 0, 0><<<dim3(32, 32), 256, 0, stream>>>(qb, kb, nullptr, Pbuf, 4096, 4096, 512, 4096);
      k_softmax_bf16<<<4096, 256, 0, stream>>>(Pbuf);
    }
    // context = P @ V  ==  P[4096,4096] * v_t[512,4096]^T
    k_gemm_bt<0, 0, 0><<<dim3(4, 32), 256, 0, stream>>>(Pbuf, vtb, nullptr, ctxb, 4096, 512, 4096, 512);
  }

  // 5) output projection (f32 out, bias)
  k_gemm_bt<1, 1, 0><<<gProj, 256, 0, stream>>>(ctx, wo_t, bo, out, 16384, 512, 512, 512);
}

// Round 2
// 469.908 us; speedup vs baseline: 1.3715x; 1.3715x over previous
//
#include <hip/hip_runtime.h>
#include <hip/hip_bf16.h>
#include <stdint.h>

#define AS1 __attribute__((address_space(1)))
#define AS3 __attribute__((address_space(3)))

typedef float f32x4 __attribute__((ext_vector_type(4)));
typedef __bf16 bf16x8 __attribute__((ext_vector_type(8)));

static __device__ __forceinline__ unsigned short f2bf(float f) {
  unsigned u = __float_as_uint(f);
  u += 0x7fff + ((u >> 16) & 1);   // RNE
  return (unsigned short)(u >> 16);
}

// ---------------- conversion kernels ----------------

__global__ __launch_bounds__(256) void k_f32_to_bf16(const float* __restrict__ in,
                                                     unsigned short* __restrict__ out, int n4) {
  int i = blockIdx.x * 256 + threadIdx.x;
  if (i >= n4) return;
  float4 v = reinterpret_cast<const float4*>(in)[i];
  ushort4 o;
  o.x = f2bf(v.x); o.y = f2bf(v.y); o.z = f2bf(v.z); o.w = f2bf(v.w);
  reinterpret_cast<ushort4*>(out)[i] = o;
}

// transpose + convert the four 512x512 weights: out[n*512+k] = bf16(w[k*512+n])
__global__ __launch_bounds__(256) void k_wtrans(const float* __restrict__ w0, const float* __restrict__ w1,
                                                const float* __restrict__ w2, const float* __restrict__ w3,
                                                unsigned short* __restrict__ o0, unsigned short* __restrict__ o1,
                                                unsigned short* __restrict__ o2, unsigned short* __restrict__ o3) {
  const float* w; unsigned short* o;
  switch (blockIdx.y) {
    case 0: w = w0; o = o0; break;
    case 1: w = w1; o = o1; break;
    case 2: w = w2; o = o2; break;
    default: w = w3; o = o3; break;
  }
  int idx = blockIdx.x * 256 + threadIdx.x;   // 0..262143
  int kk = idx >> 9;
  int n  = idx & 511;
  o[n * 512 + kk] = f2bf(w[idx]);
}

// ---------------- GEMM: C[M,N] = A[M,K] * Bt[N,K]^T (+bias) ----------------
// m97 structure: 128x128 tile, BK=32, 4 waves (each 64x64 = 4x4 frags of 16x16),
// global_load_lds width 16, mfma_f32_16x16x32_bf16.
// TRANS_OUT: write bf16 transposed per 4096-row batch: out[(gr>>12)][gc][gr&4095]
// SPLITK: blockIdx.z selects a kLen-sized K chunk; f32 partial written to
//         Cout + z*partStride.

template<int OUT_F32, int HAS_BIAS, int TRANS_OUT, int SPLITK>
__global__ __launch_bounds__(256) void k_gemm_bt(
    const unsigned short* __restrict__ A, int lda,
    const unsigned short* __restrict__ Bt, int ldb,
    const float* __restrict__ bias, void* __restrict__ Cout,
    int ldc, int kLen, int partStride)
{
  __shared__ unsigned short sA[128 * 32];
  __shared__ unsigned short sB[128 * 32];
  if (SPLITK) {
    const int z = blockIdx.z;
    A  += (size_t)z * kLen;
    Bt += (size_t)z * kLen;
    Cout = (void*)((float*)Cout + (size_t)z * partStride);
  }
  const int tid = threadIdx.x;
  const int tileM = blockIdx.y * 128;
  const int tileN = blockIdx.x * 128;
  const unsigned short* Ab = A + (size_t)tileM * lda;
  const unsigned short* Bb = Bt + (size_t)tileN * ldb;

  f32x4 acc[4][4];
#pragma unroll
  for (int m = 0; m < 4; ++m)
#pragma unroll
    for (int n = 0; n < 4; ++n)
      acc[m][n] = (f32x4){0.f, 0.f, 0.f, 0.f};

  const int lane = tid & 63;
  const int w = tid >> 6;
  const int wr = (w >> 1) * 64;
  const int wc = (w & 1) * 64;
  const int fr = lane & 15;          // fragment row (m or n within 16)
  const int fk = (lane >> 4) * 8;    // k offset within 32

  for (int k0 = 0; k0 < kLen; k0 += 32) {
    __syncthreads();
#pragma unroll
    for (int i = 0; i < 2; ++i) {
      int c = tid + i * 256;         // chunk id 0..511 (16B chunks)
      int r = c >> 2;                // row 0..127
      int cb = (c & 3) * 8;          // element offset in row (8 bf16 = 16B)
      __builtin_amdgcn_global_load_lds((const AS1 void*)(Ab + (size_t)r * lda + k0 + cb),
                                       (AS3 void*)(&sA[c * 8]), 16, 0, 0);
      __builtin_amdgcn_global_load_lds((const AS1 void*)(Bb + (size_t)r * ldb + k0 + cb),
                                       (AS3 void*)(&sB[c * 8]), 16, 0, 0);
    }
    __syncthreads();

    bf16x8 af[4], bfr[4];
#pragma unroll
    for (int m = 0; m < 4; ++m)
      af[m] = *reinterpret_cast<const bf16x8*>(&sA[(wr + m * 16 + fr) * 32 + fk]);
#pragma unroll
    for (int n = 0; n < 4; ++n)
      bfr[n] = *reinterpret_cast<const bf16x8*>(&sB[(wc + n * 16 + fr) * 32 + fk]);
#pragma unroll
    for (int m = 0; m < 4; ++m)
#pragma unroll
      for (int n = 0; n < 4; ++n)
        acc[m][n] = __builtin_amdgcn_mfma_f32_16x16x32_bf16(af[m], bfr[n], acc[m][n], 0, 0, 0);
  }

  // epilogue: C frag layout col=lane&15, row=(lane>>4)*4+reg  [m89 verified]
  const int col4 = lane & 15;
  const int rw4 = (lane >> 4) * 4;
#pragma unroll
  for (int n = 0; n < 4; ++n) {
    const int gc = tileN + wc + n * 16 + col4;
    const float bval = HAS_BIAS ? bias[gc] : 0.0f;
#pragma unroll
    for (int m = 0; m < 4; ++m) {
      const int gr = tileM + wr + m * 16 + rw4;
#pragma unroll
      for (int j = 0; j < 4; ++j) {
        float v = acc[m][n][j] + bval;
        if (TRANS_OUT) {
          size_t idx = ((size_t)((gr + j) >> 12)) * (512u * 4096u) + (size_t)gc * 4096u
                       + (size_t)((gr + j) & 4095);
          ((unsigned short*)Cout)[idx] = f2bf(v);
        } else if (OUT_F32 || SPLITK) {
          ((float*)Cout)[(size_t)(gr + j) * ldc + gc] = v;
        } else {
          ((unsigned short*)Cout)[(size_t)(gr + j) * ldc + gc] = f2bf(v);
        }
      }
    }
  }
}

// ---------------- split-K reduce: ctx = bf16(sum of 4 f32 partials) ----------

__global__ __launch_bounds__(256) void k_reduce_ks(const float* __restrict__ part,
                                                   unsigned short* __restrict__ out) {
  const int i = blockIdx.x * 256 + threadIdx.x;       // float4 index, 524288 total
  const float4* p = reinterpret_cast<const float4*>(part);
  float4 a = p[i];
  float4 b = p[i + 524288];
  float4 c = p[i + 2 * 524288];
  float4 d = p[i + 3 * 524288];
  float4 s;
  s.x = (a.x + b.x) + (c.x + d.x);
  s.y = (a.y + b.y) + (c.y + d.y);
  s.z = (a.z + b.z) + (c.z + d.z);
  s.w = (a.w + b.w) + (c.w + d.w);
  ushort4 o;
  o.x = f2bf(s.x); o.y = f2bf(s.y); o.z = f2bf(s.z); o.w = f2bf(s.w);
  reinterpret_cast<ushort4*>(out)[i] = o;
}

// ---------------- row softmax (4096 cols), one block per row ----------------

__global__ __launch_bounds__(256) void k_softmax_f32(const float* __restrict__ S,
                                                     unsigned short* __restrict__ P) {
  const int row = blockIdx.x;
  const float4* src = reinterpret_cast<const float4*>(S + (size_t)row * 4096);
  ushort4* dst = reinterpret_cast<ushort4*>(P + (size_t)row * 4096);
  const int tid = threadIdx.x;
  float4 v[4];
  float m = -3.0e38f;
#pragma unroll
  for (int i = 0; i < 4; ++i) {
    v[i] = src[tid + i * 256];
    m = fmaxf(m, fmaxf(fmaxf(v[i].x, v[i].y), fmaxf(v[i].z, v[i].w)));
  }
#pragma unroll
  for (int off = 32; off >= 1; off >>= 1) m = fmaxf(m, __shfl_xor(m, off));
  __shared__ float redm[4], reds[4];
  const int wv = tid >> 6, ln = tid & 63;
  if (ln == 0) redm[wv] = m;
  __syncthreads();
  m = fmaxf(fmaxf(redm[0], redm[1]), fmaxf(redm[2], redm[3]));
  float s = 0.f;
#pragma unroll
  for (int i = 0; i < 4; ++i) {
    v[i].x = __expf(v[i].x - m); v[i].y = __expf(v[i].y - m);
    v[i].z = __expf(v[i].z - m); v[i].w = __expf(v[i].w - m);
    s += v[i].x + v[i].y + v[i].z + v[i].w;
  }
#pragma unroll
  for (int off = 32; off >= 1; off >>= 1) s += __shfl_xor(s, off);
  if (ln == 0) reds[wv] = s;
  __syncthreads();
  s = reds[0] + reds[1] + reds[2] + reds[3];
  const float inv = 1.0f / s;
#pragma unroll
  for (int i = 0; i < 4; ++i) {
    ushort4 o;
    o.x = f2bf(v[i].x * inv); o.y = f2bf(v[i].y * inv);
    o.z = f2bf(v[i].z * inv); o.w = f2bf(v[i].w * inv);
    dst[tid + i * 256] = o;
  }
}

// fallback: scores stored bf16, softmax in place (each block touches only its own row)
__global__ __launch_bounds__(256) void k_softmax_bf16(unsigned short* __restrict__ S) {
  const int row = blockIdx.x;
  ushort4* ptr = reinterpret_cast<ushort4*>(S + (size_t)row * 4096);
  const int tid = threadIdx.x;
  float v[16];
  float m = -3.0e38f;
#pragma unroll
  for (int i = 0; i < 4; ++i) {
    ushort4 u = ptr[tid + i * 256];
    v[i * 4 + 0] = __uint_as_float(((unsigned)u.x) << 16);
    v[i * 4 + 1] = __uint_as_float(((unsigned)u.y) << 16);
    v[i * 4 + 2] = __uint_as_float(((unsigned)u.z) << 16);
    v[i * 4 + 3] = __uint_as_float(((unsigned)u.w) << 16);
#pragma unroll
    for (int j = 0; j < 4; ++j) m = fmaxf(m, v[i * 4 + j]);
  }
#pragma unroll
  for (int off = 32; off >= 1; off >>= 1) m = fmaxf(m, __shfl_xor(m, off));
  __shared__ float redm[4], reds[4];
  const int wv = tid >> 6, ln = tid & 63;
  if (ln == 0) redm[wv] = m;
  __syncthreads();
  m = fmaxf(fmaxf(redm[0], redm[1]), fmaxf(redm[2], redm[3]));
  float s = 0.f;
#pragma unroll
  for (int i = 0; i < 16; ++i) { v[i] = __expf(v[i] - m); s += v[i]; }
#pragma unroll
  for (int off = 32; off >= 1; off >>= 1) s += __shfl_xor(s, off);
  if (ln == 0) reds[wv] = s;
  __syncthreads();
  s = reds[0] + reds[1] + reds[2] + reds[3];
  const float inv = 1.0f / s;
#pragma unroll
  for (int i = 0; i < 4; ++i) {
    ushort4 o;
    o.x = f2bf(v[i * 4 + 0] * inv); o.y = f2bf(v[i * 4 + 1] * inv);
    o.z = f2bf(v[i * 4 + 2] * inv); o.w = f2bf(v[i * 4 + 3] * inv);
    ptr[tid + i * 256] = o;
  }
}

// ---------------- launch ----------------

extern "C" void kernel_launch(void* const* d_in, const int* in_sizes, int n_in,
                              void* d_out, int out_size, void* d_ws, size_t ws_size,
                              hipStream_t stream) {
  const float* query  = (const float*)d_in[0];
  const float* target = (const float*)d_in[1];
  const float* wq = (const float*)d_in[2];
  const float* bq = (const float*)d_in[3];
  const float* wk = (const float*)d_in[4];
  const float* bk = (const float*)d_in[5];
  const float* wv = (const float*)d_in[6];
  const float* bv = (const float*)d_in[7];
  const float* wo = (const float*)d_in[8];
  const float* bo = (const float*)d_in[9];
  float* out = (float*)d_out;

  const size_t NTOK = (size_t)4 * 4096;          // 16384 rows total
  const size_t SZ_BF = NTOK * 512 * sizeof(unsigned short);  // 16 MB

  char* ws = (char*)d_ws;
  size_t off = 0;
  unsigned short* query_bf  = (unsigned short*)(ws + off); off += SZ_BF;
  unsigned short* target_bf = (unsigned short*)(ws + off); off += SZ_BF;
  unsigned short* q_bf      = (unsigned short*)(ws + off); off += SZ_BF;
  unsigned short* k_bf      = (unsigned short*)(ws + off); off += SZ_BF;
  unsigned short* v_t       = (unsigned short*)(ws + off); off += SZ_BF;  // [B][512][4096]
  unsigned short* ctx       = (unsigned short*)(ws + off); off += SZ_BF;
  unsigned short* wq_t = (unsigned short*)(ws + off); off += 512 * 512 * 2;
  unsigned short* wk_t = (unsigned short*)(ws + off); off += 512 * 512 * 2;
  unsigned short* wv_t = (unsigned short*)(ws + off); off += 512 * 512 * 2;
  unsigned short* wo_t = (unsigned short*)(ws + off); off += 512 * 512 * 2;
  unsigned short* Pbuf = (unsigned short*)(ws + off); off += (size_t)4096 * 4096 * 2;  // 32 MB
  float* Sf = (float*)(ws + off);
  const bool useF32S = (ws_size >= off + (size_t)4096 * 4096 * 4);

  // split-K partial buffer (4 x 4096x512 f32 = 32 MB): aliases query_bf/target_bf,
  // which are dead after the three projection GEMMs complete (stream-ordered).
  float* partBuf = (float*)ws;

  // 1) convert inputs to bf16
  k_f32_to_bf16<<<8192, 256, 0, stream>>>(query,  query_bf,  2097152);
  k_f32_to_bf16<<<8192, 256, 0, stream>>>(target, target_bf, 2097152);
  // 2) weights -> bf16 transposed ([N][K])
  k_wtrans<<<dim3(1024, 4), 256, 0, stream>>>(wq, wk, wv, wo, wq_t, wk_t, wv_t, wo_t);

  // 3) projections  (M=16384, N=512, K=512)
  dim3 gProj(512 / 128, 16384 / 128);
  k_gemm_bt<0, 1, 0, 0><<<gProj, 256, 0, stream>>>(query_bf,  512, wq_t, 512, bq, q_bf, 512, 512, 0);
  k_gemm_bt<0, 1, 0, 0><<<gProj, 256, 0, stream>>>(target_bf, 512, wk_t, 512, bk, k_bf, 512, 512, 0);
  k_gemm_bt<0, 1, 1, 0><<<gProj, 256, 0, stream>>>(target_bf, 512, wv_t, 512, bv, v_t,  512, 512, 0);

  // 4) per-batch attention
  for (int b = 0; b < 4; ++b) {
    const unsigned short* qb  = q_bf + (size_t)b * 4096 * 512;
    const unsigned short* kb  = k_bf + (size_t)b * 4096 * 512;
    const unsigned short* vtb = v_t  + (size_t)b * 512 * 4096;
    unsigned short* ctxb = ctx + (size_t)b * 4096 * 512;
    if (useF32S) {
      k_gemm_bt<1, 0, 0, 0><<<dim3(32, 32), 256, 0, stream>>>(qb, 512, kb, 512, nullptr, Sf, 4096, 512, 0);
      k_softmax_f32<<<4096, 256, 0, stream>>>(Sf, Pbuf);
    } else {
      k_gemm_bt<0, 0, 0, 0><<<dim3(32, 32), 256, 0, stream>>>(qb, 512, kb, 512, nullptr, Pbuf, 4096, 512, 0);
      k_softmax_bf16<<<4096, 256, 0, stream>>>(Pbuf);
    }
    // context = P @ V  ==  P[4096,4096] * v_t[512,4096]^T   — split-K x4
    k_gemm_bt<1, 0, 0, 1><<<dim3(4, 32, 4), 256, 0, stream>>>(Pbuf, 4096, vtb, 4096, nullptr,
                                                              partBuf, 512, 1024, 4096 * 512);
    k_reduce_ks<<<2048, 256, 0, stream>>>(partBuf, ctxb);
  }

  // 5) output projection (f32 out, bias)
  k_gemm_bt<1, 1, 0, 0><<<gProj, 256, 0, stream>>>(ctx, 512, wo_t, 512, bo, out, 512, 512, 0);
}

// Round 3
// 434.038 us; speedup vs baseline: 1.4848x; 1.0826x over previous
//
#include <hip/hip_runtime.h>
#include <hip/hip_bf16.h>
#include <stdint.h>

#define AS1 __attribute__((address_space(1)))
#define AS3 __attribute__((address_space(3)))

typedef float f32x4 __attribute__((ext_vector_type(4)));
typedef __bf16 bf16x8 __attribute__((ext_vector_type(8)));

static __device__ __forceinline__ unsigned short f2bf(float f) {
  unsigned u = __float_as_uint(f);
  u += 0x7fff + ((u >> 16) & 1);   // RNE
  return (unsigned short)(u >> 16);
}
static __device__ __forceinline__ float bf2f_lo(unsigned u) { return __uint_as_float(u << 16); }
static __device__ __forceinline__ float bf2f_hi(unsigned u) { return __uint_as_float(u & 0xffff0000u); }

// transpose + convert the four 512x512 weights: out[n*512+k] = bf16(w[k*512+n])
__global__ __launch_bounds__(256) void k_wtrans(const float* __restrict__ w0, const float* __restrict__ w1,
                                                const float* __restrict__ w2, const float* __restrict__ w3,
                                                unsigned short* __restrict__ o0, unsigned short* __restrict__ o1,
                                                unsigned short* __restrict__ o2, unsigned short* __restrict__ o3) {
  const float* w; unsigned short* o;
  switch (blockIdx.y) {
    case 0: w = w0; o = o0; break;
    case 1: w = w1; o = o1; break;
    case 2: w = w2; o = o2; break;
    default: w = w3; o = o3; break;
  }
  int idx = blockIdx.x * 256 + threadIdx.x;   // 0..262143
  int kk = idx >> 9;
  int n  = idx & 511;
  o[n * 512 + kk] = f2bf(w[idx]);
}

// ---------------- GEMM: C[M,N] = A[M,K] * Bt[N,K]^T (+bias) ----------------
// m97 structure: 128x128 tile, BK=32, 4 waves, global_load_lds width 16,
// mfma_f32_16x16x32_bf16. C frag layout col=lane&15, row=(lane>>4)*4+reg.
// A_MODE: 0 = A is bf16, stage via global_load_lds
//         1 = A is f32, reg-stage + convert to bf16 (fused input conversion)
// EPI:    0 = bf16 out      1 = f32 out (and split-K partials)
//         2 = dual KV: cols 0-511 -> bf16 K ; cols 512-1023 -> V^T scatter
//         3 = bf16(exp(v)) out  (S-GEMM writes un-normalized softmax numerator)
// SPLITK: blockIdx.z picks a kLen K-chunk, f32 partial at CoutF + z*partStride.

template<int A_MODE, int EPI, int HAS_BIAS, int SPLITK>
__global__ __launch_bounds__(256) void k_gemm_bt(
    const void* __restrict__ Av, int lda,
    const unsigned short* __restrict__ Bt, int ldb,
    const float* __restrict__ bias, const float* __restrict__ bias2,
    void* __restrict__ Cout, void* __restrict__ Cout2,
    int ldc, int kLen, int partStride)
{
  __shared__ __align__(16) unsigned short sA[128 * 32];
  __shared__ __align__(16) unsigned short sB[128 * 32];

  const unsigned short* A16 = (const unsigned short*)Av;
  const float* A32 = (const float*)Av;
  float* CoutF = (float*)Cout;
  if (SPLITK) {
    const int z = blockIdx.z;
    A16 += (size_t)z * kLen;
    Bt  += (size_t)z * kLen;
    CoutF += (size_t)z * partStride;
  }

  const int tid = threadIdx.x;
  const int tileM = blockIdx.y * 128;
  const int tileN = blockIdx.x * 128;
  const unsigned short* Ab16 = A16 + (size_t)tileM * lda;
  const float* Ab32 = A32 + (size_t)tileM * lda;
  const unsigned short* Bb = Bt + (size_t)tileN * ldb;

  f32x4 acc[4][4];
#pragma unroll
  for (int m = 0; m < 4; ++m)
#pragma unroll
    for (int n = 0; n < 4; ++n)
      acc[m][n] = (f32x4){0.f, 0.f, 0.f, 0.f};

  const int lane = tid & 63;
  const int w = tid >> 6;
  const int wr = (w >> 1) * 64;
  const int wc = (w & 1) * 64;
  const int fr = lane & 15;
  const int fk = (lane >> 4) * 8;

  for (int k0 = 0; k0 < kLen; k0 += 32) {
    __syncthreads();
    // B tile: always bf16 via global_load_lds (16B chunks)
#pragma unroll
    for (int i = 0; i < 2; ++i) {
      int c = tid + i * 256;         // 0..511
      int r = c >> 2;
      int cb = (c & 3) * 8;
      __builtin_amdgcn_global_load_lds((const AS1 void*)(Bb + (size_t)r * ldb + k0 + cb),
                                       (AS3 void*)(&sB[c * 8]), 16, 0, 0);
    }
    // A tile
    if (A_MODE == 0) {
#pragma unroll
      for (int i = 0; i < 2; ++i) {
        int c = tid + i * 256;
        int r = c >> 2;
        int cb = (c & 3) * 8;
        __builtin_amdgcn_global_load_lds((const AS1 void*)(Ab16 + (size_t)r * lda + k0 + cb),
                                         (AS3 void*)(&sA[c * 8]), 16, 0, 0);
      }
    } else {
      // f32 source: load float4, convert to 4 bf16, ds_write 8B
#pragma unroll
      for (int i = 0; i < 4; ++i) {
        int c = tid + i * 256;       // 0..1023 (8B units)
        int r = c >> 3;
        int co = (c & 7) * 4;
        float4 f = *(const float4*)(Ab32 + (size_t)r * lda + k0 + co);
        ushort4 h;
        h.x = f2bf(f.x); h.y = f2bf(f.y); h.z = f2bf(f.z); h.w = f2bf(f.w);
        reinterpret_cast<ushort4*>(sA)[c] = h;
      }
    }
    __syncthreads();

    bf16x8 af[4], bfr[4];
#pragma unroll
    for (int m = 0; m < 4; ++m)
      af[m] = *reinterpret_cast<const bf16x8*>(&sA[(wr + m * 16 + fr) * 32 + fk]);
#pragma unroll
    for (int n = 0; n < 4; ++n)
      bfr[n] = *reinterpret_cast<const bf16x8*>(&sB[(wc + n * 16 + fr) * 32 + fk]);
#pragma unroll
    for (int m = 0; m < 4; ++m)
#pragma unroll
      for (int n = 0; n < 4; ++n)
        acc[m][n] = __builtin_amdgcn_mfma_f32_16x16x32_bf16(af[m], bfr[n], acc[m][n], 0, 0, 0);
  }

  const int col4 = lane & 15;
  const int rw4 = (lane >> 4) * 4;
#pragma unroll
  for (int n = 0; n < 4; ++n) {
    const int gc = tileN + wc + n * 16 + col4;
    float bval = 0.f;
    if (HAS_BIAS) bval = (EPI == 2) ? (gc < 512 ? bias[gc] : bias2[gc - 512]) : bias[gc];
#pragma unroll
    for (int m = 0; m < 4; ++m) {
      const int gr0 = tileM + wr + m * 16 + rw4;
#pragma unroll
      for (int j = 0; j < 4; ++j) {
        const int gr = gr0 + j;
        float v = acc[m][n][j] + bval;
        if (EPI == 1) {
          CoutF[(size_t)gr * ldc + gc] = v;
        } else if (EPI == 0) {
          ((unsigned short*)Cout)[(size_t)gr * ldc + gc] = f2bf(v);
        } else if (EPI == 3) {
          ((unsigned short*)Cout)[(size_t)gr * ldc + gc] = f2bf(__expf(v));
        } else {  // EPI == 2: dual K | V^T
          if (gc < 512) {
            ((unsigned short*)Cout)[(size_t)gr * 512 + gc] = f2bf(v);
          } else {
            ((unsigned short*)Cout2)[((size_t)(gr >> 12)) * 2097152u
                                     + (size_t)(gc - 512) * 4096u
                                     + (size_t)(gr & 4095)] = f2bf(v);
          }
        }
      }
    }
  }
}

// ---------------- row sum of E = exp(S): invl[row] = 1 / sum ----------------

__global__ __launch_bounds__(256) void k_rowsum(const unsigned short* __restrict__ E,
                                                float* __restrict__ invl) {
  const int row = blockIdx.x;
  const uint4* p = reinterpret_cast<const uint4*>(E + (size_t)row * 4096);
  const int tid = threadIdx.x;
  float s = 0.f;
#pragma unroll
  for (int i = 0; i < 2; ++i) {
    uint4 u = p[tid + i * 256];
    s += bf2f_lo(u.x) + bf2f_hi(u.x) + bf2f_lo(u.y) + bf2f_hi(u.y)
       + bf2f_lo(u.z) + bf2f_hi(u.z) + bf2f_lo(u.w) + bf2f_hi(u.w);
  }
#pragma unroll
  for (int off = 32; off >= 1; off >>= 1) s += __shfl_xor(s, off);
  __shared__ float reds[4];
  const int wv = tid >> 6, ln = tid & 63;
  if (ln == 0) reds[wv] = s;
  __syncthreads();
  if (tid == 0) {
    float t = reds[0] + reds[1] + reds[2] + reds[3];
    invl[row] = 1.0f / t;
  }
}

// ------- split-K reduce + softmax normalization: ctx = bf16(sum * invl) ------

__global__ __launch_bounds__(256) void k_reduce_ks(const float* __restrict__ part,
                                                   const float* __restrict__ invl,
                                                   unsigned short* __restrict__ out) {
  const int i = blockIdx.x * 256 + threadIdx.x;       // float4 index, 524288 total
  const float4* p = reinterpret_cast<const float4*>(part);
  float4 a = p[i];
  float4 b = p[i + 524288];
  float4 c = p[i + 2 * 524288];
  float4 d = p[i + 3 * 524288];
  const float iv = invl[i >> 7];                      // 128 float4 per 512-col row
  float4 s;
  s.x = ((a.x + b.x) + (c.x + d.x)) * iv;
  s.y = ((a.y + b.y) + (c.y + d.y)) * iv;
  s.z = ((a.z + b.z) + (c.z + d.z)) * iv;
  s.w = ((a.w + b.w) + (c.w + d.w)) * iv;
  ushort4 o;
  o.x = f2bf(s.x); o.y = f2bf(s.y); o.z = f2bf(s.z); o.w = f2bf(s.w);
  reinterpret_cast<ushort4*>(out)[i] = o;
}

// ---------------- launch ----------------

extern "C" void kernel_launch(void* const* d_in, const int* in_sizes, int n_in,
                              void* d_out, int out_size, void* d_ws, size_t ws_size,
                              hipStream_t stream) {
  const float* query  = (const float*)d_in[0];
  const float* target = (const float*)d_in[1];
  const float* wq = (const float*)d_in[2];
  const float* bq = (const float*)d_in[3];
  const float* wk = (const float*)d_in[4];
  const float* bk = (const float*)d_in[5];
  const float* wv = (const float*)d_in[6];
  const float* bv = (const float*)d_in[7];
  const float* wo = (const float*)d_in[8];
  const float* bo = (const float*)d_in[9];
  float* out = (float*)d_out;

  const size_t SZ_BF = (size_t)16384 * 512 * 2;       // 16 MB

  char* ws = (char*)d_ws;
  size_t off = 0;
  unsigned short* q_bf = (unsigned short*)(ws + off); off += SZ_BF;
  unsigned short* k_bf = (unsigned short*)(ws + off); off += SZ_BF;
  unsigned short* v_t  = (unsigned short*)(ws + off); off += SZ_BF;   // [B][512][4096]
  unsigned short* ctx  = (unsigned short*)(ws + off); off += SZ_BF;
  unsigned short* wq_t  = (unsigned short*)(ws + off); off += 512 * 512 * 2;
  unsigned short* wkv_t = (unsigned short*)(ws + off); off += 2 * 512 * 512 * 2;  // wk rows 0-511, wv rows 512-1023
  unsigned short* wo_t  = (unsigned short*)(ws + off); off += 512 * 512 * 2;
  unsigned short* Sbuf  = (unsigned short*)(ws + off); off += (size_t)4096 * 4096 * 2;  // 32 MB, per-batch reuse
  float* invl = (float*)(ws + off); off += 4096 * sizeof(float);
  float* part = (float*)(ws + off); off += (size_t)4 * 4096 * 512 * 4;  // 32 MB
  (void)ws_size;

  // 1) weights -> bf16 transposed ([N][K]); wk/wv packed contiguously for the dual GEMM
  k_wtrans<<<dim3(1024, 4), 256, 0, stream>>>(wq, wk, wv, wo,
                                              wq_t, wkv_t, wkv_t + 512 * 512, wo_t);

  // 2) projections with fused f32->bf16 A-conversion  (M=16384, K=512)
  k_gemm_bt<1, 0, 1, 0><<<dim3(4, 128), 256, 0, stream>>>(
      query, 512, wq_t, 512, bq, nullptr, q_bf, nullptr, 512, 512, 0);
  // K and V share the A (target) pass: N=1024 dual epilogue
  k_gemm_bt<1, 2, 1, 0><<<dim3(8, 128), 256, 0, stream>>>(
      target, 512, wkv_t, 512, bk, bv, k_bf, v_t, 512, 512, 0);

  // 3) per-batch attention
  for (int b = 0; b < 4; ++b) {
    const unsigned short* qb  = q_bf + (size_t)b * 4096 * 512;
    const unsigned short* kb  = k_bf + (size_t)b * 4096 * 512;
    const unsigned short* vtb = v_t  + (size_t)b * 512 * 4096;
    unsigned short* ctxb = ctx + (size_t)b * 4096 * 512;

    // E = exp(Q K^T)   (un-normalized softmax numerator, bf16)
    k_gemm_bt<0, 3, 0, 0><<<dim3(32, 32), 256, 0, stream>>>(
        qb, 512, kb, 512, nullptr, nullptr, Sbuf, nullptr, 4096, 512, 0);
    // l = row-sum, invl = 1/l
    k_rowsum<<<4096, 256, 0, stream>>>(Sbuf, invl);
    // partial = E @ V  (split-K x4, f32 partials)
    k_gemm_bt<0, 1, 0, 1><<<dim3(4, 32, 4), 256, 0, stream>>>(
        Sbuf, 4096, vtb, 4096, nullptr, nullptr, part, nullptr, 512, 1024, 4096 * 512);
    // ctx = bf16((sum of partials) * invl)
    k_reduce_ks<<<2048, 256, 0, stream>>>(part, invl, ctxb);
  }

  // 4) output projection (f32 out, bias)
  k_gemm_bt<0, 1, 1, 0><<<dim3(4, 128), 256, 0, stream>>>(
      ctx, 512, wo_t, 512, bo, nullptr, out, nullptr, 512, 512, 0);
}